// Round 6
// baseline (1070.410 us; speedup 1.0000x reference)
//
#include <hip/hip_runtime.h>

// Problem constants
constexpr int cB = 2, cT = 2048, cE = 1024, cH = 16, cD = 64, cBH = 32, cN = 4096;

typedef __attribute__((ext_vector_type(8))) short bf16x8;
typedef __attribute__((ext_vector_type(4))) float f32x4;
typedef _Float16 f16x8 __attribute__((ext_vector_type(8)));

static __device__ __forceinline__ unsigned short bf16_rne(float f) {
    unsigned u = __float_as_uint(f);
    unsigned r = u + 0x7fffu + ((u >> 16) & 1u);
    return (unsigned short)(r >> 16);
}
static __device__ __forceinline__ float bf16_f(unsigned short h) {
    return __uint_as_float(((unsigned)h) << 16);
}
static __device__ __forceinline__ unsigned short f16_bits(_Float16 h) {
    union { _Float16 f; unsigned short u; } c; c.f = h; return c.u;
}

// LDS row stride (shorts) for 64-col attention tiles: 68 -> 52.2 KB/block
// => 3 blocks/CU (was 72 -> 55.3 KB -> 2 blocks/CU). 136B stride keeps
// ds_read_b128 bank load perfectly balanced (8 dword-accesses/bank).
constexpr int LS = 68;

// ---------------------------------------------------------------------------
// GEMM: C[m][n] = (sum_k A[m][k]*B[n][k] + bias[n]) * scale
// M=4096, N=1024, K=1024.
// T14 prefetch: next k-tile's global loads issued after the LDS-write
// barrier, so HBM latency hides under the MFMA phase of the current tile.
// ---------------------------------------------------------------------------
template<int PASSES, int AF32>
__global__ __launch_bounds__(256, 2)
void gemm_x(const void* __restrict__ Ap, const float* __restrict__ Bp,
            const float* __restrict__ bias, float scale,
            float* __restrict__ Cf) {
    __shared__ __attribute__((aligned(16))) unsigned short sAh[128 * 40];
    __shared__ __attribute__((aligned(16))) unsigned short sBh[128 * 40];
    __shared__ __attribute__((aligned(16))) unsigned short sAl[(PASSES == 3) ? 128 * 40 : 8];
    __shared__ __attribute__((aligned(16))) unsigned short sBl[(PASSES == 3) ? 128 * 40 : 8];

    const int tid = threadIdx.x;
    const int lane = tid & 63;
    const int wid = tid >> 6;
    const int m0 = blockIdx.y * 128, n0 = blockIdx.x * 128;
    const int wm = (wid >> 1) * 64, wn = (wid & 1) * 64;
    const int fr = lane & 15, kq = (lane >> 4) * 8;
    const int ldr = tid >> 1, ldc = (tid & 1) * 16;

    f32x4 acc[4][4];
    for (int i = 0; i < 4; i++)
        for (int j = 0; j < 4; j++)
            acc[i][j] = f32x4{0.f, 0.f, 0.f, 0.f};

    float av[16];
    float bv[16];
    bf16x8 abh0, abh1;   // used when AF32==0

    // ---- prologue: load tile k0=0 into registers ----
    if constexpr (AF32) {
        const float* ga = (const float*)Ap + (size_t)(m0 + ldr) * 1024 + ldc;
        for (int u = 0; u < 4; u++) {
            f32x4 t = *(const f32x4*)(ga + u * 4);
            av[u * 4 + 0] = t[0]; av[u * 4 + 1] = t[1];
            av[u * 4 + 2] = t[2]; av[u * 4 + 3] = t[3];
        }
    } else {
        const unsigned short* ga = (const unsigned short*)Ap + (size_t)(m0 + ldr) * 1024 + ldc;
        abh0 = *(const bf16x8*)ga;
        abh1 = *(const bf16x8*)(ga + 8);
    }
    {
        const float* gb = Bp + (size_t)(n0 + ldr) * 1024 + ldc;
        for (int u = 0; u < 4; u++) {
            f32x4 t = *(const f32x4*)(gb + u * 4);
            bv[u * 4 + 0] = t[0]; bv[u * 4 + 1] = t[1];
            bv[u * 4 + 2] = t[2]; bv[u * 4 + 3] = t[3];
        }
    }

    for (int k0 = 0; k0 < 1024; k0 += 32) {
        __syncthreads();   // prior tile's MFMA done reading LDS
        // ---- convert & store current regs to LDS ----
        if constexpr (AF32) {
            bf16x8 h0, h1, l0, l1;
            for (int u = 0; u < 8; u++) {
                unsigned short h = bf16_rne(av[u]);
                h0[u] = (short)h;
                if constexpr (PASSES == 3) l0[u] = (short)bf16_rne(av[u] - bf16_f(h));
            }
            for (int u = 0; u < 8; u++) {
                unsigned short h = bf16_rne(av[8 + u]);
                h1[u] = (short)h;
                if constexpr (PASSES == 3) l1[u] = (short)bf16_rne(av[8 + u] - bf16_f(h));
            }
            *(bf16x8*)&sAh[ldr * 40 + ldc] = h0; *(bf16x8*)&sAh[ldr * 40 + ldc + 8] = h1;
            if constexpr (PASSES == 3) {
                *(bf16x8*)&sAl[ldr * 40 + ldc] = l0; *(bf16x8*)&sAl[ldr * 40 + ldc + 8] = l1;
            }
        } else {
            *(bf16x8*)&sAh[ldr * 40 + ldc] = abh0; *(bf16x8*)&sAh[ldr * 40 + ldc + 8] = abh1;
        }
        {
            bf16x8 h0, h1, l0, l1;
            for (int u = 0; u < 8; u++) {
                unsigned short h = bf16_rne(bv[u]);
                h0[u] = (short)h;
                if constexpr (PASSES == 3) l0[u] = (short)bf16_rne(bv[u] - bf16_f(h));
            }
            for (int u = 0; u < 8; u++) {
                unsigned short h = bf16_rne(bv[8 + u]);
                h1[u] = (short)h;
                if constexpr (PASSES == 3) l1[u] = (short)bf16_rne(bv[8 + u] - bf16_f(h));
            }
            *(bf16x8*)&sBh[ldr * 40 + ldc] = h0; *(bf16x8*)&sBh[ldr * 40 + ldc + 8] = h1;
            if constexpr (PASSES == 3) {
                *(bf16x8*)&sBl[ldr * 40 + ldc] = l0; *(bf16x8*)&sBl[ldr * 40 + ldc + 8] = l1;
            }
        }
        __syncthreads();   // writes visible

        // ---- prefetch next tile; latency hides under MFMA below ----
        if (k0 + 32 < 1024) {
            if constexpr (AF32) {
                const float* ga = (const float*)Ap + (size_t)(m0 + ldr) * 1024 + k0 + 32 + ldc;
                for (int u = 0; u < 4; u++) {
                    f32x4 t = *(const f32x4*)(ga + u * 4);
                    av[u * 4 + 0] = t[0]; av[u * 4 + 1] = t[1];
                    av[u * 4 + 2] = t[2]; av[u * 4 + 3] = t[3];
                }
            } else {
                const unsigned short* ga = (const unsigned short*)Ap + (size_t)(m0 + ldr) * 1024 + k0 + 32 + ldc;
                abh0 = *(const bf16x8*)ga;
                abh1 = *(const bf16x8*)(ga + 8);
            }
            const float* gb = Bp + (size_t)(n0 + ldr) * 1024 + k0 + 32 + ldc;
            for (int u = 0; u < 4; u++) {
                f32x4 t = *(const f32x4*)(gb + u * 4);
                bv[u * 4 + 0] = t[0]; bv[u * 4 + 1] = t[1];
                bv[u * 4 + 2] = t[2]; bv[u * 4 + 3] = t[3];
            }
        }

        bf16x8 fa[4], fb[4];
        for (int i = 0; i < 4; i++) fa[i] = *(const bf16x8*)&sAh[(wm + i * 16 + fr) * 40 + kq];
        for (int j = 0; j < 4; j++) fb[j] = *(const bf16x8*)&sBh[(wn + j * 16 + fr) * 40 + kq];
        if constexpr (PASSES == 3) {
            bf16x8 fal[4], fbl[4];
            for (int i = 0; i < 4; i++) fal[i] = *(const bf16x8*)&sAl[(wm + i * 16 + fr) * 40 + kq];
            for (int j = 0; j < 4; j++) fbl[j] = *(const bf16x8*)&sBl[(wn + j * 16 + fr) * 40 + kq];
            for (int i = 0; i < 4; i++)
                for (int j = 0; j < 4; j++) {
                    acc[i][j] = __builtin_amdgcn_mfma_f32_16x16x32_bf16(fa[i], fb[j], acc[i][j], 0, 0, 0);
                    acc[i][j] = __builtin_amdgcn_mfma_f32_16x16x32_bf16(fa[i], fbl[j], acc[i][j], 0, 0, 0);
                    acc[i][j] = __builtin_amdgcn_mfma_f32_16x16x32_bf16(fal[i], fb[j], acc[i][j], 0, 0, 0);
                }
        } else {
            for (int i = 0; i < 4; i++)
                for (int j = 0; j < 4; j++)
                    acc[i][j] = __builtin_amdgcn_mfma_f32_16x16x32_bf16(fa[i], fb[j], acc[i][j], 0, 0, 0);
        }
    }

    for (int j = 0; j < 4; j++) {
        int col = n0 + wn + j * 16 + fr;
        float bvs = bias[col];
        for (int i = 0; i < 4; i++) {
            int rbase = m0 + wm + i * 16 + (lane >> 4) * 4;
            f32x4 v = acc[i][j];
            for (int r = 0; r < 4; r++) {
                float o = (v[r] + bvs) * scale;
                Cf[(size_t)(rbase + r) * 1024 + col] = o;
            }
        }
    }
}

// ---------------------------------------------------------------------------
// Exact top-512-of-1024 pruning (radix select, index-ordered ties) + xPos.
// mode 0: q (xpos up-scale) -> split bf16; 1: k (downscale) -> split bf16;
// 2: v -> F16 (dl unused; PV runs f16 MFMA). [BH][T][D] layout.
// ---------------------------------------------------------------------------
__global__ __launch_bounds__(256)
void prune_xpos(const float* __restrict__ src, int mode,
                unsigned short* __restrict__ dh, unsigned short* __restrict__ dl) {
    const int row = blockIdx.x;      // b*T + t
    const int tid = threadIdx.x;

    __shared__ float xs[1024];
    __shared__ unsigned su[1024];
    __shared__ unsigned hist[256];
    __shared__ unsigned s_pref;
    __shared__ int s_kneed;

    for (int q = 0; q < 4; q++) {
        int j = tid + q * 256;
        float v = src[(size_t)row * 1024 + j];
        xs[j] = v;
        unsigned u = __float_as_uint(v);
        u ^= (u & 0x80000000u) ? 0xFFFFFFFFu : 0x80000000u;
        su[j] = u;
    }
    __syncthreads();

    unsigned pref = 0;
    int kneed = 512;
    for (int shift = 24; shift >= 0; shift -= 8) {
        hist[tid] = 0;
        __syncthreads();
        for (int q = 0; q < 4; q++) {
            unsigned u = su[tid + q * 256];
            bool ok = (shift == 24) || ((u >> (shift + 8)) == (pref >> (shift + 8)));
            if (ok) atomicAdd(&hist[(u >> shift) & 255], 1u);
        }
        __syncthreads();
        for (int off = 1; off < 256; off <<= 1) {
            unsigned add = (tid + off < 256) ? hist[tid + off] : 0u;
            __syncthreads();
            hist[tid] += add;
            __syncthreads();
        }
        unsigned ge = hist[tid];
        unsigned gt = (tid == 255) ? 0u : hist[tid + 1];
        if ((int)ge >= kneed && (int)gt < kneed) {
            s_pref = pref | ((unsigned)tid << shift);
            s_kneed = kneed - (int)gt;
        }
        __syncthreads();
        pref = s_pref;
        kneed = s_kneed;
        __syncthreads();
    }

    const unsigned ustar = pref;
    unsigned myeq[4];
    for (int q = 0; q < 4; q++) myeq[q] = (su[tid + q * 256] == ustar) ? 1u : 0u;
    __syncthreads();
    for (int q = 0; q < 4; q++) su[tid + q * 256] = myeq[q];
    __syncthreads();
    for (int off = 1; off < 1024; off <<= 1) {
        unsigned add[4];
        for (int q = 0; q < 4; q++) {
            int j = tid + q * 256;
            add[q] = (j >= off) ? su[j - off] : 0u;
        }
        __syncthreads();
        for (int q = 0; q < 4; q++) su[tid + q * 256] += add[q];
        __syncthreads();
    }
    for (int q = 0; q < 4; q++) {
        int j = tid + q * 256;
        unsigned u = __float_as_uint(xs[j]);
        u ^= (u & 0x80000000u) ? 0xFFFFFFFFu : 0x80000000u;
        bool keep = (u > ustar) || (myeq[q] && (int)(su[j] - 1u) < kneed);
        if (!keep) xs[j] = 0.f;
    }
    __syncthreads();

    const int b = row >> 11;
    const int t = row & 2047;
    if (mode == 2) {
        for (int q = 0; q < 4; q++) {
            int j = tid + q * 256;
            int h = j >> 6, d = j & 63;
            dh[((size_t)(b * cH + h) * cT + t) * cD + d] = f16_bits((_Float16)xs[j]);
        }
    } else {
        for (int pj = tid; pj < 512; pj += 256) {
            int h = pj >> 5;
            int i = pj & 31;
            int j0 = h * 64 + 2 * i;
            float x0 = xs[j0], x1 = xs[j0 + 1];
            float base = (2.f * (float)i + 25.6f) / 89.6f;
            float p = ((float)t - 1024.f) * (1.f / 512.f);
            float sc = powf(base, p);
            if (mode == 1) sc = 1.f / sc;
            float pw = powf(10000.f, (float)i * (1.f / 32.f));
            float invf = 1.f / pw;
            float ang = (float)t * invf;
            float sn = sinf(ang) * sc;
            float cs = cosf(ang) * sc;
            float y0 = x0 * cs - x1 * sn;
            float y1 = x1 * cs + x0 * sn;
            size_t bi = ((size_t)(b * cH + h) * cT + t) * cD;
            unsigned short h0 = bf16_rne(y0);
            unsigned short h1 = bf16_rne(y1);
            dh[bi + 2 * i] = h0;
            dh[bi + 2 * i + 1] = h1;
            dl[bi + 2 * i] = bf16_rne(y0 - bf16_f(h0));
            dl[bi + 2 * i + 1] = bf16_rne(y1 - bf16_f(h1));
        }
    }
}

// ---------------------------------------------------------------------------
// v transpose: [BH][T][D] -> [BH][D][T]  (16-bit payload, dtype-agnostic)
// ---------------------------------------------------------------------------
__global__ __launch_bounds__(256)
void transpose_v(const unsigned short* __restrict__ vh, unsigned short* __restrict__ vt) {
    const int bh = blockIdx.y;
    const int s0 = blockIdx.x * 64;
    const int tid = threadIdx.x;
    __shared__ __attribute__((aligned(16))) unsigned short tile[64 * 72];
    {
        int r = tid >> 2, c = (tid & 3) * 16;
        const unsigned short* g = vh + ((size_t)bh * cT + s0 + r) * cD + c;
        bf16x8 v0 = *(const bf16x8*)g, v1 = *(const bf16x8*)(g + 8);
        *(bf16x8*)&tile[r * 72 + c] = v0;
        *(bf16x8*)&tile[r * 72 + c + 8] = v1;
    }
    __syncthreads();
    int d = tid >> 2, c = (tid & 3) * 16;
    bf16x8 o0, o1;
    for (int i = 0; i < 8; i++) o0[i] = (short)tile[(c + i) * 72 + d];
    for (int i = 0; i < 8; i++) o1[i] = (short)tile[(c + 8 + i) * 72 + d];
    unsigned short* dst = vt + ((size_t)bh * cD + d) * cT + s0 + c;
    *(bf16x8*)dst = o0;
    *(bf16x8*)(dst + 8) = o1;
}

// split-bf16 QK accumulation — identical sequence in both passes -> bitwise-equal scores
// T5: setprio(1) around the MFMA cluster (attn-structure +4-7%, m191)
static __device__ __forceinline__ f32x4 qk6(bf16x8 ah0, bf16x8 ah1, bf16x8 al0, bf16x8 al1,
                                            bf16x8 bh0, bf16x8 bh1, bf16x8 bl0, bf16x8 bl1) {
    f32x4 acc{0.f, 0.f, 0.f, 0.f};
    __builtin_amdgcn_s_setprio(1);
    acc = __builtin_amdgcn_mfma_f32_16x16x32_bf16(ah0, bh0, acc, 0, 0, 0);
    acc = __builtin_amdgcn_mfma_f32_16x16x32_bf16(ah1, bh1, acc, 0, 0, 0);
    acc = __builtin_amdgcn_mfma_f32_16x16x32_bf16(ah0, bl0, acc, 0, 0, 0);
    acc = __builtin_amdgcn_mfma_f32_16x16x32_bf16(ah1, bl1, acc, 0, 0, 0);
    acc = __builtin_amdgcn_mfma_f32_16x16x32_bf16(al0, bh0, acc, 0, 0, 0);
    acc = __builtin_amdgcn_mfma_f32_16x16x32_bf16(al1, bh1, acc, 0, 0, 0);
    __builtin_amdgcn_s_setprio(0);
    return acc;
}

// ---------------------------------------------------------------------------
// Attention pass 1: per-row max m and sum l of exp(s-m)
// T14 reorder + one-expf online update. LDS stride 68 + bounds(256,3):
// 3 blocks/CU (was 2) for +50% latency-hiding waves.
// ---------------------------------------------------------------------------
__global__ __launch_bounds__(256, 3)
void attn_ml(const unsigned short* __restrict__ qhh, const unsigned short* __restrict__ qhl,
             const unsigned short* __restrict__ khh, const unsigned short* __restrict__ khl,
             float* __restrict__ mrow, float* __restrict__ lrow) {
    const int bh = blockIdx.y;
    const int q0 = blockIdx.x * 64;
    const int tid = threadIdx.x, lane = tid & 63, wid = tid >> 6;
    const int fr = lane & 15, kq = (lane >> 4) * 8, g = lane >> 4;

    __shared__ __attribute__((aligned(16))) unsigned short qsh[64 * LS];
    __shared__ __attribute__((aligned(16))) unsigned short qsl[64 * LS];
    __shared__ __attribute__((aligned(16))) unsigned short ksh[128 * LS];
    __shared__ __attribute__((aligned(16))) unsigned short ksl[128 * LS];

    {
        int r = tid >> 2, c = (tid & 3) * 16;
        size_t off = ((size_t)bh * cT + q0 + r) * cD + c;
        bf16x8 a = *(const bf16x8*)(qhh + off), b = *(const bf16x8*)(qhh + off + 8);
        bf16x8 cc = *(const bf16x8*)(qhl + off), d = *(const bf16x8*)(qhl + off + 8);
        *(bf16x8*)&qsh[r * LS + c] = a; *(bf16x8*)&qsh[r * LS + c + 8] = b;
        *(bf16x8*)&qsl[r * LS + c] = cc; *(bf16x8*)&qsl[r * LS + c + 8] = d;
    }
    __syncthreads();
    bf16x8 ah0 = *(const bf16x8*)&qsh[(wid * 16 + fr) * LS + kq];
    bf16x8 ah1 = *(const bf16x8*)&qsh[(wid * 16 + fr) * LS + 32 + kq];
    bf16x8 al0 = *(const bf16x8*)&qsl[(wid * 16 + fr) * LS + kq];
    bf16x8 al1 = *(const bf16x8*)&qsl[(wid * 16 + fr) * LS + 32 + kq];

    float mloc[4], lloc[4];
    for (int r = 0; r < 4; r++) { mloc[r] = -3.0e38f; lloc[r] = 0.f; }

    const int sr = tid >> 1, sc0 = (tid & 1) * 32;
    bf16x8 u0, u1, u2, u3, w0, w1, w2, w3;
    {   // prologue: stage tile 0 into registers
        size_t off = ((size_t)bh * cT + sr) * cD + sc0;
        u0 = *(const bf16x8*)(khh + off);
        u1 = *(const bf16x8*)(khh + off + 8);
        u2 = *(const bf16x8*)(khh + off + 16);
        u3 = *(const bf16x8*)(khh + off + 24);
        w0 = *(const bf16x8*)(khl + off);
        w1 = *(const bf16x8*)(khl + off + 8);
        w2 = *(const bf16x8*)(khl + off + 16);
        w3 = *(const bf16x8*)(khl + off + 24);
    }

    for (int s0 = 0; s0 < cT; s0 += 128) {
        __syncthreads();   // prior tile's compute done reading LDS
        *(bf16x8*)&ksh[sr * LS + sc0] = u0;      *(bf16x8*)&ksh[sr * LS + sc0 + 8] = u1;
        *(bf16x8*)&ksh[sr * LS + sc0 + 16] = u2; *(bf16x8*)&ksh[sr * LS + sc0 + 24] = u3;
        *(bf16x8*)&ksl[sr * LS + sc0] = w0;      *(bf16x8*)&ksl[sr * LS + sc0 + 8] = w1;
        *(bf16x8*)&ksl[sr * LS + sc0 + 16] = w2; *(bf16x8*)&ksl[sr * LS + sc0 + 24] = w3;
        __syncthreads();
        if (s0 + 128 < cT) {   // issue next tile loads; latency hides under compute below
            size_t off = ((size_t)bh * cT + s0 + 128 + sr) * cD + sc0;
            u0 = *(const bf16x8*)(khh + off);
            u1 = *(const bf16x8*)(khh + off + 8);
            u2 = *(const bf16x8*)(khh + off + 16);
            u3 = *(const bf16x8*)(khh + off + 24);
            w0 = *(const bf16x8*)(khl + off);
            w1 = *(const bf16x8*)(khl + off + 8);
            w2 = *(const bf16x8*)(khl + off + 16);
            w3 = *(const bf16x8*)(khl + off + 24);
        }
        for (int j = 0; j < 8; j++) {
            bf16x8 bh0 = *(const bf16x8*)&ksh[(j * 16 + fr) * LS + kq];
            bf16x8 bh1 = *(const bf16x8*)&ksh[(j * 16 + fr) * LS + 32 + kq];
            bf16x8 bl0 = *(const bf16x8*)&ksl[(j * 16 + fr) * LS + kq];
            bf16x8 bl1 = *(const bf16x8*)&ksl[(j * 16 + fr) * LS + 32 + kq];
            f32x4 acc = qk6(ah0, ah1, al0, al1, bh0, bh1, bl0, bl1);
            for (int r4 = 0; r4 < 4; r4++) {
                // one-expf online update; bitwise-identical to the 2-expf form
                float s = acc[r4];
                float d = s - mloc[r4];
                float e = expf(-fabsf(d));
                if (d > 0.f) { lloc[r4] = lloc[r4] * e + 1.f; mloc[r4] = s; }
                else         { lloc[r4] += e; }
            }
        }
    }
    for (int off = 1; off < 16; off <<= 1) {
        for (int r4 = 0; r4 < 4; r4++) {
            float mo = __shfl_xor(mloc[r4], off, 64);
            float lo = __shfl_xor(lloc[r4], off, 64);
            float mn = fmaxf(mloc[r4], mo);
            lloc[r4] = lloc[r4] * expf(mloc[r4] - mn) + lo * expf(mo - mn);
            mloc[r4] = mn;
        }
    }
    if (fr == 0) {
        for (int r4 = 0; r4 < 4; r4++) {
            int qr = q0 + wid * 16 + g * 4 + r4;
            mrow[(size_t)bh * cT + qr] = mloc[r4];
            lrow[(size_t)bh * cT + qr] = lloc[r4];
        }
    }
}

// ---------------------------------------------------------------------------
// Attention pass 2: recompute scores, write fp32(f16(softmax)) weights
// (nontemporal), PV via f16 MFMA. LDS stride 68 + bounds(256,3):
// 3 blocks/CU (was 2). T14 prefetch of next K/V tile.
// ---------------------------------------------------------------------------
__global__ __launch_bounds__(256, 3)
void attn_wv(const unsigned short* __restrict__ qhh, const unsigned short* __restrict__ qhl,
             const unsigned short* __restrict__ khh, const unsigned short* __restrict__ khl,
             const unsigned short* __restrict__ vt,
             const float* __restrict__ mrow, const float* __restrict__ lrow,
             float* __restrict__ out1, unsigned short* __restrict__ attnb) {
    const int bh = blockIdx.y;
    const int b = bh >> 4, h = bh & 15;
    const int q0 = blockIdx.x * 64;
    const int tid = threadIdx.x, lane = tid & 63, wid = tid >> 6;
    const int fr = lane & 15, kq = (lane >> 4) * 8, g = lane >> 4;

    __shared__ __attribute__((aligned(16))) unsigned short qsh[64 * LS];
    __shared__ __attribute__((aligned(16))) unsigned short qsl[64 * LS];
    __shared__ __attribute__((aligned(16))) unsigned short ksh[64 * LS];
    __shared__ __attribute__((aligned(16))) unsigned short ksl[64 * LS];
    __shared__ __attribute__((aligned(16))) unsigned short vs[64 * LS];
    __shared__ __attribute__((aligned(16))) unsigned short psh[64 * LS];   // f16 probs

    {
        int r = tid >> 2, c = (tid & 3) * 16;
        size_t off = ((size_t)bh * cT + q0 + r) * cD + c;
        bf16x8 a = *(const bf16x8*)(qhh + off), bb = *(const bf16x8*)(qhh + off + 8);
        bf16x8 cc = *(const bf16x8*)(qhl + off), d = *(const bf16x8*)(qhl + off + 8);
        *(bf16x8*)&qsh[r * LS + c] = a; *(bf16x8*)&qsh[r * LS + c + 8] = bb;
        *(bf16x8*)&qsl[r * LS + c] = cc; *(bf16x8*)&qsl[r * LS + c + 8] = d;
    }
    __syncthreads();
    bf16x8 ah0 = *(const bf16x8*)&qsh[(wid * 16 + fr) * LS + kq];
    bf16x8 ah1 = *(const bf16x8*)&qsh[(wid * 16 + fr) * LS + 32 + kq];
    bf16x8 al0 = *(const bf16x8*)&qsl[(wid * 16 + fr) * LS + kq];
    bf16x8 al1 = *(const bf16x8*)&qsl[(wid * 16 + fr) * LS + 32 + kq];

    float mloc[4], linv[4];
    for (int r4 = 0; r4 < 4; r4++) {
        int qr = q0 + wid * 16 + g * 4 + r4;
        mloc[r4] = mrow[(size_t)bh * cT + qr];
        linv[r4] = 1.f / lrow[(size_t)bh * cT + qr];
    }
    f32x4 od[4];
    for (int nf = 0; nf < 4; nf++) od[nf] = f32x4{0.f, 0.f, 0.f, 0.f};

    const int sr = tid >> 2, sc = (tid & 3) * 16;
    bf16x8 k0, k1, k2, k3, v0, v1;
    {   // prologue: stage tile 0 into registers
        size_t koff = ((size_t)bh * cT + sr) * cD + sc;
        k0 = *(const bf16x8*)(khh + koff); k1 = *(const bf16x8*)(khh + koff + 8);
        k2 = *(const bf16x8*)(khl + koff); k3 = *(const bf16x8*)(khl + koff + 8);
        size_t voff = ((size_t)bh * cD + sr) * cT + sc;
        v0 = *(const bf16x8*)(vt + voff);  v1 = *(const bf16x8*)(vt + voff + 8);
    }

    for (int s0 = 0; s0 < cT; s0 += 64) {
        __syncthreads();   // prior tile's PV done reading LDS
        *(bf16x8*)&ksh[sr * LS + sc] = k0; *(bf16x8*)&ksh[sr * LS + sc + 8] = k1;
        *(bf16x8*)&ksl[sr * LS + sc] = k2; *(bf16x8*)&ksl[sr * LS + sc + 8] = k3;
        *(bf16x8*)&vs[sr * LS + sc] = v0;  *(bf16x8*)&vs[sr * LS + sc + 8] = v1;
        __syncthreads();
        if (s0 + 64 < cT) {   // issue next tile loads; covered by QK+softmax+PV below
            size_t koff = ((size_t)bh * cT + s0 + 64 + sr) * cD + sc;
            k0 = *(const bf16x8*)(khh + koff); k1 = *(const bf16x8*)(khh + koff + 8);
            k2 = *(const bf16x8*)(khl + koff); k3 = *(const bf16x8*)(khl + koff + 8);
            size_t voff = ((size_t)bh * cD + sr) * cT + s0 + 64 + sc;
            v0 = *(const bf16x8*)(vt + voff);  v1 = *(const bf16x8*)(vt + voff + 8);
        }
        for (int j = 0; j < 4; j++) {
            bf16x8 bh0 = *(const bf16x8*)&ksh[(j * 16 + fr) * LS + kq];
            bf16x8 bh1 = *(const bf16x8*)&ksh[(j * 16 + fr) * LS + 32 + kq];
            bf16x8 bl0 = *(const bf16x8*)&ksl[(j * 16 + fr) * LS + kq];
            bf16x8 bl1 = *(const bf16x8*)&ksl[(j * 16 + fr) * LS + 32 + kq];
            f32x4 acc = qk6(ah0, ah1, al0, al1, bh0, bh1, bl0, bl1);
            int scol = s0 + j * 16 + fr;
            for (int r4 = 0; r4 < 4; r4++) {
                float p = expf(acc[r4] - mloc[r4]) * linv[r4];
                _Float16 p16 = (_Float16)p;           // reference casts w to f16
                float pf = (float)p16;                // exact
                int qrl = wid * 16 + g * 4 + r4;
                psh[qrl * LS + j * 16 + fr] = f16_bits(p16);   // f16 MFMA operand
                size_t oidx = ((size_t)((h * cB + b) * cT + q0 + qrl)) * cT + scol;
                __builtin_nontemporal_store(pf, &out1[oidx]);  // write-once stream
            }
        }
        __syncthreads();
        __builtin_amdgcn_s_setprio(1);
        for (int kc = 0; kc < 2; kc++) {
            f16x8 pa = *(const f16x8*)&psh[(wid * 16 + fr) * LS + kc * 32 + kq];
            for (int nf = 0; nf < 4; nf++) {
                f16x8 vb = *(const f16x8*)&vs[(nf * 16 + fr) * LS + kc * 32 + kq];
                od[nf] = __builtin_amdgcn_mfma_f32_16x16x32_f16(pa, vb, od[nf], 0, 0, 0);
            }
        }
        __builtin_amdgcn_s_setprio(0);
    }
    for (int nf = 0; nf < 4; nf++) {
        for (int r4 = 0; r4 < 4; r4++) {
            int qr = q0 + wid * 16 + g * 4 + r4;
            int col = h * cD + nf * 16 + fr;
            attnb[(size_t)(b * cT + qr) * cE + col] = bf16_rne(od[nf][r4]);
        }
    }
}

// ---------------------------------------------------------------------------
// Launch — workspace footprint 56 MB (unchanged layout)
// ---------------------------------------------------------------------------
extern "C" void kernel_launch(void* const* d_in, const int* in_sizes, int n_in,
                              void* d_out, int out_size, void* d_ws, size_t ws_size,
                              hipStream_t stream) {
    (void)in_sizes; (void)n_in; (void)out_size; (void)ws_size;
    const float* query = (const float*)d_in[0];
    const float* key   = (const float*)d_in[1];
    const float* value = (const float*)d_in[2];
    const float* Wq = (const float*)d_in[3];
    const float* bq = (const float*)d_in[4];
    const float* Wk = (const float*)d_in[5];
    const float* bk = (const float*)d_in[6];
    const float* Wv = (const float*)d_in[7];
    const float* bv = (const float*)d_in[8];
    const float* Wo = (const float*)d_in[9];
    const float* bo = (const float*)d_in[10];

    char* w = (char*)d_ws;
    unsigned short* qhh = (unsigned short*)(w + 0);
    unsigned short* qhl = (unsigned short*)(w + 8388608);
    unsigned short* khh = (unsigned short*)(w + 16777216);
    unsigned short* khl = (unsigned short*)(w + 25165824);
    float*          proj = (float*)(w + 33554432);          // 16 MB, per-phase
    unsigned short* vt   = (unsigned short*)(w + 33554432); // overlays proj (dead)
    unsigned short* attnb = (unsigned short*)(w + 41943040);// overlays proj high half
    unsigned short* vh  = (unsigned short*)(w + 50331648);  // 8 MB
    float* mrow = (float*)(w + 50331648);                   // overlays vh (dead after transpose)
    float* lrow = (float*)(w + 50593792);

    float* out0 = (float*)d_out;
    float* out1 = out0 + (size_t)cN * cE;

    dim3 blk(256);
    dim3 gg(8, 32);

    // q: project (fp32 in, split-bf16 3-pass), scale by D^-0.5, prune+xpos
    gemm_x<3, 1><<<gg, blk, 0, stream>>>(query, Wq, bq, 0.125f, proj);
    prune_xpos<<<dim3(cN), blk, 0, stream>>>(proj, 0, qhh, qhl);
    // k
    gemm_x<3, 1><<<gg, blk, 0, stream>>>(key, Wk, bk, 1.0f, proj);
    prune_xpos<<<dim3(cN), blk, 0, stream>>>(proj, 1, khh, khl);
    // v (f16, 1-pass)
    gemm_x<1, 1><<<gg, blk, 0, stream>>>(value, Wv, bv, 1.0f, proj);
    prune_xpos<<<dim3(cN), blk, 0, stream>>>(proj, 2, vh, nullptr);

    transpose_v<<<dim3(cT / 64, cBH), blk, 0, stream>>>(vh, vt);
    attn_ml<<<dim3(cT / 64, cBH), blk, 0, stream>>>(qhh, qhl, khh, khl, mrow, lrow);
    attn_wv<<<dim3(cT / 64, cBH), blk, 0, stream>>>(qhh, qhl, khh, khl, vt, mrow, lrow, out1, attnb);

    // out0 = attnb @ Wo^T + bo  (A bf16, B fp32->bf16 in-kernel), fp32 out
    gemm_x<1, 0><<<gg, blk, 0, stream>>>(attnb, Wo, bo, 1.0f, out0);
}

// Round 7
// 1030.538 us; speedup vs baseline: 1.0387x; 1.0387x over previous
//
#include <hip/hip_runtime.h>

// Problem constants
constexpr int cB = 2, cT = 2048, cE = 1024, cH = 16, cD = 64, cBH = 32, cN = 4096;

typedef __attribute__((ext_vector_type(8))) short bf16x8;
typedef __attribute__((ext_vector_type(4))) float f32x4;
typedef _Float16 f16x8 __attribute__((ext_vector_type(8)));

static __device__ __forceinline__ unsigned short bf16_rne(float f) {
    unsigned u = __float_as_uint(f);
    unsigned r = u + 0x7fffu + ((u >> 16) & 1u);
    return (unsigned short)(r >> 16);
}
static __device__ __forceinline__ float bf16_f(unsigned short h) {
    return __uint_as_float(((unsigned)h) << 16);
}
static __device__ __forceinline__ unsigned short f16_bits(_Float16 h) {
    union { _Float16 f; unsigned short u; } c; c.f = h; return c.u;
}

// ---------------------------------------------------------------------------
// Pre-split fp32 -> bf16 hi/lo. Up to 3 segments per launch (blocks of 2048
// elements each; 256 thr x 8 elem). Segment 3 and dl==nullptr are h-only.
// Hoists the per-tile conversion out of gemm_x (was redone 8-32x per tile).
// ---------------------------------------------------------------------------
__global__ __launch_bounds__(256)
void split_hl3(const float* __restrict__ s1, unsigned short* __restrict__ h1,
               unsigned short* __restrict__ l1, int n1,
               const float* __restrict__ s2, unsigned short* __restrict__ h2,
               unsigned short* __restrict__ l2, int n2,
               const float* __restrict__ s3, unsigned short* __restrict__ h3) {
    const int b = blockIdx.x;
    const float* s; unsigned short* dh; unsigned short* dl;
    if (b < n1) {
        size_t o = (size_t)b * 2048;
        s = s1 + o; dh = h1 + o; dl = (l1 ? l1 + o : nullptr);
    } else if (b < n1 + n2) {
        size_t o = (size_t)(b - n1) * 2048;
        s = s2 + o; dh = h2 + o; dl = (l2 ? l2 + o : nullptr);
    } else {
        size_t o = (size_t)(b - n1 - n2) * 2048;
        s = s3 + o; dh = h3 + o; dl = nullptr;
    }
    const int t = threadIdx.x * 8;
    f32x4 a = *(const f32x4*)(s + t);
    f32x4 bb = *(const f32x4*)(s + t + 4);
    float v[8] = {a[0], a[1], a[2], a[3], bb[0], bb[1], bb[2], bb[3]};
    bf16x8 h, l;
    for (int u = 0; u < 8; u++) {
        unsigned short hh = bf16_rne(v[u]);
        h[u] = (short)hh;
        l[u] = (short)bf16_rne(v[u] - bf16_f(hh));
    }
    *(bf16x8*)(dh + t) = h;
    if (dl) *(bf16x8*)(dl + t) = l;
}

// ---------------------------------------------------------------------------
// GEMM: C[m][n] = (sum_k A[m][k]*B[n][k] + bias[n]) * scale
// M=4096, N=1024, K=1024.
// AMODE: 0 = A bf16 (single); 1 = A fp32, in-kernel h-convert (PASSES==1);
//        2 = A pre-split bf16 h/l. B is always pre-split bf16 (h, +l if P==3).
// T14 prefetch: next k-tile's global loads issued after the LDS-write barrier.
// ---------------------------------------------------------------------------
template<int PASSES, int AMODE>
__global__ __launch_bounds__(256, 2)
void gemm_x(const unsigned short* __restrict__ Ah, const unsigned short* __restrict__ Al,
            const float* __restrict__ Af,
            const unsigned short* __restrict__ Bh, const unsigned short* __restrict__ Bl,
            const float* __restrict__ bias, float scale,
            float* __restrict__ Cf) {
    __shared__ __attribute__((aligned(16))) unsigned short sAh[128 * 40];
    __shared__ __attribute__((aligned(16))) unsigned short sBh[128 * 40];
    __shared__ __attribute__((aligned(16))) unsigned short sAl[(PASSES == 3) ? 128 * 40 : 8];
    __shared__ __attribute__((aligned(16))) unsigned short sBl[(PASSES == 3) ? 128 * 40 : 8];

    const int tid = threadIdx.x;
    const int lane = tid & 63;
    const int wid = tid >> 6;
    const int m0 = blockIdx.y * 128, n0 = blockIdx.x * 128;
    const int wm = (wid >> 1) * 64, wn = (wid & 1) * 64;
    const int fr = lane & 15, kq = (lane >> 4) * 8;
    const int ldr = tid >> 1, ldc = (tid & 1) * 16;

    f32x4 acc[4][4];
    for (int i = 0; i < 4; i++)
        for (int j = 0; j < 4; j++)
            acc[i][j] = f32x4{0.f, 0.f, 0.f, 0.f};

    bf16x8 rah0, rah1, ral0, ral1;   // AMODE 0/2
    float av[16];                    // AMODE 1
    bf16x8 rbh0, rbh1, rbl0, rbl1;

    // ---- prologue: load tile k0=0 into registers ----
    {
        if constexpr (AMODE == 1) {
            const float* ga = Af + (size_t)(m0 + ldr) * 1024 + ldc;
            for (int u = 0; u < 4; u++) {
                f32x4 t = *(const f32x4*)(ga + u * 4);
                av[u * 4 + 0] = t[0]; av[u * 4 + 1] = t[1];
                av[u * 4 + 2] = t[2]; av[u * 4 + 3] = t[3];
            }
        } else {
            const unsigned short* ga = Ah + (size_t)(m0 + ldr) * 1024 + ldc;
            rah0 = *(const bf16x8*)ga; rah1 = *(const bf16x8*)(ga + 8);
            if constexpr (AMODE == 2 && PASSES == 3) {
                const unsigned short* gl = Al + (size_t)(m0 + ldr) * 1024 + ldc;
                ral0 = *(const bf16x8*)gl; ral1 = *(const bf16x8*)(gl + 8);
            }
        }
        const unsigned short* gb = Bh + (size_t)(n0 + ldr) * 1024 + ldc;
        rbh0 = *(const bf16x8*)gb; rbh1 = *(const bf16x8*)(gb + 8);
        if constexpr (PASSES == 3) {
            const unsigned short* gl = Bl + (size_t)(n0 + ldr) * 1024 + ldc;
            rbl0 = *(const bf16x8*)gl; rbl1 = *(const bf16x8*)(gl + 8);
        }
    }

    for (int k0 = 0; k0 < 1024; k0 += 32) {
        __syncthreads();   // prior tile's MFMA done reading LDS
        // ---- store current regs to LDS (convert only for AMODE==1) ----
        if constexpr (AMODE == 1) {
            bf16x8 h0, h1;
            for (int u = 0; u < 8; u++) h0[u] = (short)bf16_rne(av[u]);
            for (int u = 0; u < 8; u++) h1[u] = (short)bf16_rne(av[8 + u]);
            *(bf16x8*)&sAh[ldr * 40 + ldc] = h0; *(bf16x8*)&sAh[ldr * 40 + ldc + 8] = h1;
        } else {
            *(bf16x8*)&sAh[ldr * 40 + ldc] = rah0; *(bf16x8*)&sAh[ldr * 40 + ldc + 8] = rah1;
            if constexpr (AMODE == 2 && PASSES == 3) {
                *(bf16x8*)&sAl[ldr * 40 + ldc] = ral0; *(bf16x8*)&sAl[ldr * 40 + ldc + 8] = ral1;
            }
        }
        *(bf16x8*)&sBh[ldr * 40 + ldc] = rbh0; *(bf16x8*)&sBh[ldr * 40 + ldc + 8] = rbh1;
        if constexpr (PASSES == 3) {
            *(bf16x8*)&sBl[ldr * 40 + ldc] = rbl0; *(bf16x8*)&sBl[ldr * 40 + ldc + 8] = rbl1;
        }
        __syncthreads();   // writes visible

        // ---- prefetch next tile; latency hides under MFMA below ----
        if (k0 + 32 < 1024) {
            if constexpr (AMODE == 1) {
                const float* ga = Af + (size_t)(m0 + ldr) * 1024 + k0 + 32 + ldc;
                for (int u = 0; u < 4; u++) {
                    f32x4 t = *(const f32x4*)(ga + u * 4);
                    av[u * 4 + 0] = t[0]; av[u * 4 + 1] = t[1];
                    av[u * 4 + 2] = t[2]; av[u * 4 + 3] = t[3];
                }
            } else {
                const unsigned short* ga = Ah + (size_t)(m0 + ldr) * 1024 + k0 + 32 + ldc;
                rah0 = *(const bf16x8*)ga; rah1 = *(const bf16x8*)(ga + 8);
                if constexpr (AMODE == 2 && PASSES == 3) {
                    const unsigned short* gl = Al + (size_t)(m0 + ldr) * 1024 + k0 + 32 + ldc;
                    ral0 = *(const bf16x8*)gl; ral1 = *(const bf16x8*)(gl + 8);
                }
            }
            const unsigned short* gb = Bh + (size_t)(n0 + ldr) * 1024 + k0 + 32 + ldc;
            rbh0 = *(const bf16x8*)gb; rbh1 = *(const bf16x8*)(gb + 8);
            if constexpr (PASSES == 3) {
                const unsigned short* gl = Bl + (size_t)(n0 + ldr) * 1024 + k0 + 32 + ldc;
                rbl0 = *(const bf16x8*)gl; rbl1 = *(const bf16x8*)(gl + 8);
            }
        }

        bf16x8 fa[4], fb[4];
        for (int i = 0; i < 4; i++) fa[i] = *(const bf16x8*)&sAh[(wm + i * 16 + fr) * 40 + kq];
        for (int j = 0; j < 4; j++) fb[j] = *(const bf16x8*)&sBh[(wn + j * 16 + fr) * 40 + kq];
        if constexpr (PASSES == 3) {
            bf16x8 fal[4], fbl[4];
            for (int i = 0; i < 4; i++) fal[i] = *(const bf16x8*)&sAl[(wm + i * 16 + fr) * 40 + kq];
            for (int j = 0; j < 4; j++) fbl[j] = *(const bf16x8*)&sBl[(wn + j * 16 + fr) * 40 + kq];
            for (int i = 0; i < 4; i++)
                for (int j = 0; j < 4; j++) {
                    acc[i][j] = __builtin_amdgcn_mfma_f32_16x16x32_bf16(fa[i], fb[j], acc[i][j], 0, 0, 0);
                    acc[i][j] = __builtin_amdgcn_mfma_f32_16x16x32_bf16(fa[i], fbl[j], acc[i][j], 0, 0, 0);
                    acc[i][j] = __builtin_amdgcn_mfma_f32_16x16x32_bf16(fal[i], fb[j], acc[i][j], 0, 0, 0);
                }
        } else {
            for (int i = 0; i < 4; i++)
                for (int j = 0; j < 4; j++)
                    acc[i][j] = __builtin_amdgcn_mfma_f32_16x16x32_bf16(fa[i], fb[j], acc[i][j], 0, 0, 0);
        }
    }

    for (int j = 0; j < 4; j++) {
        int col = n0 + wn + j * 16 + fr;
        float bvs = bias[col];
        for (int i = 0; i < 4; i++) {
            int rbase = m0 + wm + i * 16 + (lane >> 4) * 4;
            f32x4 v = acc[i][j];
            for (int r = 0; r < 4; r++) {
                float o = (v[r] + bvs) * scale;
                Cf[(size_t)(rbase + r) * 1024 + col] = o;
            }
        }
    }
}

// ---------------------------------------------------------------------------
// Exact top-512-of-1024 pruning (radix select, index-ordered ties) + xPos.
// mode 0: q -> split bf16; 1: k (downscale) -> split bf16; 2: v -> F16.
// ---------------------------------------------------------------------------
__global__ __launch_bounds__(256)
void prune_xpos(const float* __restrict__ src, int mode,
                unsigned short* __restrict__ dh, unsigned short* __restrict__ dl) {
    const int row = blockIdx.x;      // b*T + t
    const int tid = threadIdx.x;

    __shared__ float xs[1024];
    __shared__ unsigned su[1024];
    __shared__ unsigned hist[256];
    __shared__ unsigned s_pref;
    __shared__ int s_kneed;

    for (int q = 0; q < 4; q++) {
        int j = tid + q * 256;
        float v = src[(size_t)row * 1024 + j];
        xs[j] = v;
        unsigned u = __float_as_uint(v);
        u ^= (u & 0x80000000u) ? 0xFFFFFFFFu : 0x80000000u;
        su[j] = u;
    }
    __syncthreads();

    unsigned pref = 0;
    int kneed = 512;
    for (int shift = 24; shift >= 0; shift -= 8) {
        hist[tid] = 0;
        __syncthreads();
        for (int q = 0; q < 4; q++) {
            unsigned u = su[tid + q * 256];
            bool ok = (shift == 24) || ((u >> (shift + 8)) == (pref >> (shift + 8)));
            if (ok) atomicAdd(&hist[(u >> shift) & 255], 1u);
        }
        __syncthreads();
        for (int off = 1; off < 256; off <<= 1) {
            unsigned add = (tid + off < 256) ? hist[tid + off] : 0u;
            __syncthreads();
            hist[tid] += add;
            __syncthreads();
        }
        unsigned ge = hist[tid];
        unsigned gt = (tid == 255) ? 0u : hist[tid + 1];
        if ((int)ge >= kneed && (int)gt < kneed) {
            s_pref = pref | ((unsigned)tid << shift);
            s_kneed = kneed - (int)gt;
        }
        __syncthreads();
        pref = s_pref;
        kneed = s_kneed;
        __syncthreads();
    }

    const unsigned ustar = pref;
    unsigned myeq[4];
    for (int q = 0; q < 4; q++) myeq[q] = (su[tid + q * 256] == ustar) ? 1u : 0u;
    __syncthreads();
    for (int q = 0; q < 4; q++) su[tid + q * 256] = myeq[q];
    __syncthreads();
    for (int off = 1; off < 1024; off <<= 1) {
        unsigned add[4];
        for (int q = 0; q < 4; q++) {
            int j = tid + q * 256;
            add[q] = (j >= off) ? su[j - off] : 0u;
        }
        __syncthreads();
        for (int q = 0; q < 4; q++) su[tid + q * 256] += add[q];
        __syncthreads();
    }
    for (int q = 0; q < 4; q++) {
        int j = tid + q * 256;
        unsigned u = __float_as_uint(xs[j]);
        u ^= (u & 0x80000000u) ? 0xFFFFFFFFu : 0x80000000u;
        bool keep = (u > ustar) || (myeq[q] && (int)(su[j] - 1u) < kneed);
        if (!keep) xs[j] = 0.f;
    }
    __syncthreads();

    const int b = row >> 11;
    const int t = row & 2047;
    if (mode == 2) {
        for (int q = 0; q < 4; q++) {
            int j = tid + q * 256;
            int h = j >> 6, d = j & 63;
            dh[((size_t)(b * cH + h) * cT + t) * cD + d] = f16_bits((_Float16)xs[j]);
        }
    } else {
        for (int pj = tid; pj < 512; pj += 256) {
            int h = pj >> 5;
            int i = pj & 31;
            int j0 = h * 64 + 2 * i;
            float x0 = xs[j0], x1 = xs[j0 + 1];
            float base = (2.f * (float)i + 25.6f) / 89.6f;
            float p = ((float)t - 1024.f) * (1.f / 512.f);
            float sc = powf(base, p);
            if (mode == 1) sc = 1.f / sc;
            float pw = powf(10000.f, (float)i * (1.f / 32.f));
            float invf = 1.f / pw;
            float ang = (float)t * invf;
            float sn = sinf(ang) * sc;
            float cs = cosf(ang) * sc;
            float y0 = x0 * cs - x1 * sn;
            float y1 = x1 * cs + x0 * sn;
            size_t bi = ((size_t)(b * cH + h) * cT + t) * cD;
            unsigned short h0 = bf16_rne(y0);
            unsigned short h1 = bf16_rne(y1);
            dh[bi + 2 * i] = h0;
            dh[bi + 2 * i + 1] = h1;
            dl[bi + 2 * i] = bf16_rne(y0 - bf16_f(h0));
            dl[bi + 2 * i + 1] = bf16_rne(y1 - bf16_f(h1));
        }
    }
}

// ---------------------------------------------------------------------------
// v transpose: [BH][T][D] -> [BH][D][T]  (16-bit payload, dtype-agnostic)
// ---------------------------------------------------------------------------
__global__ __launch_bounds__(256)
void transpose_v(const unsigned short* __restrict__ vh, unsigned short* __restrict__ vt) {
    const int bh = blockIdx.y;
    const int s0 = blockIdx.x * 64;
    const int tid = threadIdx.x;
    __shared__ __attribute__((aligned(16))) unsigned short tile[64 * 72];
    {
        int r = tid >> 2, c = (tid & 3) * 16;
        const unsigned short* g = vh + ((size_t)bh * cT + s0 + r) * cD + c;
        bf16x8 v0 = *(const bf16x8*)g, v1 = *(const bf16x8*)(g + 8);
        *(bf16x8*)&tile[r * 72 + c] = v0;
        *(bf16x8*)&tile[r * 72 + c + 8] = v1;
    }
    __syncthreads();
    int d = tid >> 2, c = (tid & 3) * 16;
    bf16x8 o0, o1;
    for (int i = 0; i < 8; i++) o0[i] = (short)tile[(c + i) * 72 + d];
    for (int i = 0; i < 8; i++) o1[i] = (short)tile[(c + 8 + i) * 72 + d];
    unsigned short* dst = vt + ((size_t)bh * cD + d) * cT + s0 + c;
    *(bf16x8*)dst = o0;
    *(bf16x8*)(dst + 8) = o1;
}

// split-bf16 QK accumulation — identical sequence in both passes -> bitwise-equal scores
static __device__ __forceinline__ f32x4 qk6(bf16x8 ah0, bf16x8 ah1, bf16x8 al0, bf16x8 al1,
                                            bf16x8 bh0, bf16x8 bh1, bf16x8 bl0, bf16x8 bl1) {
    f32x4 acc{0.f, 0.f, 0.f, 0.f};
    __builtin_amdgcn_s_setprio(1);
    acc = __builtin_amdgcn_mfma_f32_16x16x32_bf16(ah0, bh0, acc, 0, 0, 0);
    acc = __builtin_amdgcn_mfma_f32_16x16x32_bf16(ah1, bh1, acc, 0, 0, 0);
    acc = __builtin_amdgcn_mfma_f32_16x16x32_bf16(ah0, bl0, acc, 0, 0, 0);
    acc = __builtin_amdgcn_mfma_f32_16x16x32_bf16(ah1, bl1, acc, 0, 0, 0);
    acc = __builtin_amdgcn_mfma_f32_16x16x32_bf16(al0, bh0, acc, 0, 0, 0);
    acc = __builtin_amdgcn_mfma_f32_16x16x32_bf16(al1, bh1, acc, 0, 0, 0);
    __builtin_amdgcn_s_setprio(0);
    return acc;
}

// ---------------------------------------------------------------------------
// Attention pass 1: per-row max m and sum l of exp(s-m)
// R5 config (measured best): stride 72, bounds(256,2). T14 reorder + one-expf.
// ---------------------------------------------------------------------------
__global__ __launch_bounds__(256, 2)
void attn_ml(const unsigned short* __restrict__ qhh, const unsigned short* __restrict__ qhl,
             const unsigned short* __restrict__ khh, const unsigned short* __restrict__ khl,
             float* __restrict__ mrow, float* __restrict__ lrow) {
    const int bh = blockIdx.y;
    const int q0 = blockIdx.x * 64;
    const int tid = threadIdx.x, lane = tid & 63, wid = tid >> 6;
    const int fr = lane & 15, kq = (lane >> 4) * 8, g = lane >> 4;

    __shared__ __attribute__((aligned(16))) unsigned short qsh[64 * 72];
    __shared__ __attribute__((aligned(16))) unsigned short qsl[64 * 72];
    __shared__ __attribute__((aligned(16))) unsigned short ksh[128 * 72];
    __shared__ __attribute__((aligned(16))) unsigned short ksl[128 * 72];

    {
        int r = tid >> 2, c = (tid & 3) * 16;
        size_t off = ((size_t)bh * cT + q0 + r) * cD + c;
        bf16x8 a = *(const bf16x8*)(qhh + off), b = *(const bf16x8*)(qhh + off + 8);
        bf16x8 cc = *(const bf16x8*)(qhl + off), d = *(const bf16x8*)(qhl + off + 8);
        *(bf16x8*)&qsh[r * 72 + c] = a; *(bf16x8*)&qsh[r * 72 + c + 8] = b;
        *(bf16x8*)&qsl[r * 72 + c] = cc; *(bf16x8*)&qsl[r * 72 + c + 8] = d;
    }
    __syncthreads();
    bf16x8 ah0 = *(const bf16x8*)&qsh[(wid * 16 + fr) * 72 + kq];
    bf16x8 ah1 = *(const bf16x8*)&qsh[(wid * 16 + fr) * 72 + 32 + kq];
    bf16x8 al0 = *(const bf16x8*)&qsl[(wid * 16 + fr) * 72 + kq];
    bf16x8 al1 = *(const bf16x8*)&qsl[(wid * 16 + fr) * 72 + 32 + kq];

    float mloc[4], lloc[4];
    for (int r = 0; r < 4; r++) { mloc[r] = -3.0e38f; lloc[r] = 0.f; }

    const int sr = tid >> 1, sc0 = (tid & 1) * 32;
    bf16x8 u0, u1, u2, u3, w0, w1, w2, w3;
    {   // prologue: stage tile 0 into registers
        size_t off = ((size_t)bh * cT + sr) * cD + sc0;
        u0 = *(const bf16x8*)(khh + off);
        u1 = *(const bf16x8*)(khh + off + 8);
        u2 = *(const bf16x8*)(khh + off + 16);
        u3 = *(const bf16x8*)(khh + off + 24);
        w0 = *(const bf16x8*)(khl + off);
        w1 = *(const bf16x8*)(khl + off + 8);
        w2 = *(const bf16x8*)(khl + off + 16);
        w3 = *(const bf16x8*)(khl + off + 24);
    }

    for (int s0 = 0; s0 < cT; s0 += 128) {
        __syncthreads();   // prior tile's compute done reading LDS
        *(bf16x8*)&ksh[sr * 72 + sc0] = u0;      *(bf16x8*)&ksh[sr * 72 + sc0 + 8] = u1;
        *(bf16x8*)&ksh[sr * 72 + sc0 + 16] = u2; *(bf16x8*)&ksh[sr * 72 + sc0 + 24] = u3;
        *(bf16x8*)&ksl[sr * 72 + sc0] = w0;      *(bf16x8*)&ksl[sr * 72 + sc0 + 8] = w1;
        *(bf16x8*)&ksl[sr * 72 + sc0 + 16] = w2; *(bf16x8*)&ksl[sr * 72 + sc0 + 24] = w3;
        __syncthreads();
        if (s0 + 128 < cT) {   // issue next tile loads; latency hides under compute below
            size_t off = ((size_t)bh * cT + s0 + 128 + sr) * cD + sc0;
            u0 = *(const bf16x8*)(khh + off);
            u1 = *(const bf16x8*)(khh + off + 8);
            u2 = *(const bf16x8*)(khh + off + 16);
            u3 = *(const bf16x8*)(khh + off + 24);
            w0 = *(const bf16x8*)(khl + off);
            w1 = *(const bf16x8*)(khl + off + 8);
            w2 = *(const bf16x8*)(khl + off + 16);
            w3 = *(const bf16x8*)(khl + off + 24);
        }
        for (int j = 0; j < 8; j++) {
            bf16x8 bh0 = *(const bf16x8*)&ksh[(j * 16 + fr) * 72 + kq];
            bf16x8 bh1 = *(const bf16x8*)&ksh[(j * 16 + fr) * 72 + 32 + kq];
            bf16x8 bl0 = *(const bf16x8*)&ksl[(j * 16 + fr) * 72 + kq];
            bf16x8 bl1 = *(const bf16x8*)&ksl[(j * 16 + fr) * 72 + 32 + kq];
            f32x4 acc = qk6(ah0, ah1, al0, al1, bh0, bh1, bl0, bl1);
            for (int r4 = 0; r4 < 4; r4++) {
                // one-expf online update; bitwise-identical to the 2-expf form
                float s = acc[r4];
                float d = s - mloc[r4];
                float e = expf(-fabsf(d));
                if (d > 0.f) { lloc[r4] = lloc[r4] * e + 1.f; mloc[r4] = s; }
                else         { lloc[r4] += e; }
            }
        }
    }
    for (int off = 1; off < 16; off <<= 1) {
        for (int r4 = 0; r4 < 4; r4++) {
            float mo = __shfl_xor(mloc[r4], off, 64);
            float lo = __shfl_xor(lloc[r4], off, 64);
            float mn = fmaxf(mloc[r4], mo);
            lloc[r4] = lloc[r4] * expf(mloc[r4] - mn) + lo * expf(mo - mn);
            mloc[r4] = mn;
        }
    }
    if (fr == 0) {
        for (int r4 = 0; r4 < 4; r4++) {
            int qr = q0 + wid * 16 + g * 4 + r4;
            mrow[(size_t)bh * cT + qr] = mloc[r4];
            lrow[(size_t)bh * cT + qr] = lloc[r4];
        }
    }
}

// ---------------------------------------------------------------------------
// Attention pass 2: recompute scores, write fp32(f16(softmax)) weights
// (nontemporal), PV via f16 MFMA. R5 config: stride 72, bounds(256,2).
// ---------------------------------------------------------------------------
__global__ __launch_bounds__(256, 2)
void attn_wv(const unsigned short* __restrict__ qhh, const unsigned short* __restrict__ qhl,
             const unsigned short* __restrict__ khh, const unsigned short* __restrict__ khl,
             const unsigned short* __restrict__ vt,
             const float* __restrict__ mrow, const float* __restrict__ lrow,
             float* __restrict__ out1, unsigned short* __restrict__ attnb) {
    const int bh = blockIdx.y;
    const int b = bh >> 4, h = bh & 15;
    const int q0 = blockIdx.x * 64;
    const int tid = threadIdx.x, lane = tid & 63, wid = tid >> 6;
    const int fr = lane & 15, kq = (lane >> 4) * 8, g = lane >> 4;

    __shared__ __attribute__((aligned(16))) unsigned short qsh[64 * 72];
    __shared__ __attribute__((aligned(16))) unsigned short qsl[64 * 72];
    __shared__ __attribute__((aligned(16))) unsigned short ksh[64 * 72];
    __shared__ __attribute__((aligned(16))) unsigned short ksl[64 * 72];
    __shared__ __attribute__((aligned(16))) unsigned short vs[64 * 72];
    __shared__ __attribute__((aligned(16))) unsigned short psh[64 * 72];   // f16 probs

    {
        int r = tid >> 2, c = (tid & 3) * 16;
        size_t off = ((size_t)bh * cT + q0 + r) * cD + c;
        bf16x8 a = *(const bf16x8*)(qhh + off), bb = *(const bf16x8*)(qhh + off + 8);
        bf16x8 cc = *(const bf16x8*)(qhl + off), d = *(const bf16x8*)(qhl + off + 8);
        *(bf16x8*)&qsh[r * 72 + c] = a; *(bf16x8*)&qsh[r * 72 + c + 8] = bb;
        *(bf16x8*)&qsl[r * 72 + c] = cc; *(bf16x8*)&qsl[r * 72 + c + 8] = d;
    }
    __syncthreads();
    bf16x8 ah0 = *(const bf16x8*)&qsh[(wid * 16 + fr) * 72 + kq];
    bf16x8 ah1 = *(const bf16x8*)&qsh[(wid * 16 + fr) * 72 + 32 + kq];
    bf16x8 al0 = *(const bf16x8*)&qsl[(wid * 16 + fr) * 72 + kq];
    bf16x8 al1 = *(const bf16x8*)&qsl[(wid * 16 + fr) * 72 + 32 + kq];

    float mloc[4], linv[4];
    for (int r4 = 0; r4 < 4; r4++) {
        int qr = q0 + wid * 16 + g * 4 + r4;
        mloc[r4] = mrow[(size_t)bh * cT + qr];
        linv[r4] = 1.f / lrow[(size_t)bh * cT + qr];
    }
    f32x4 od[4];
    for (int nf = 0; nf < 4; nf++) od[nf] = f32x4{0.f, 0.f, 0.f, 0.f};

    const int sr = tid >> 2, sc = (tid & 3) * 16;
    bf16x8 k0, k1, k2, k3, v0, v1;
    {   // prologue: stage tile 0 into registers
        size_t koff = ((size_t)bh * cT + sr) * cD + sc;
        k0 = *(const bf16x8*)(khh + koff); k1 = *(const bf16x8*)(khh + koff + 8);
        k2 = *(const bf16x8*)(khl + koff); k3 = *(const bf16x8*)(khl + koff + 8);
        size_t voff = ((size_t)bh * cD + sr) * cT + sc;
        v0 = *(const bf16x8*)(vt + voff);  v1 = *(const bf16x8*)(vt + voff + 8);
    }

    for (int s0 = 0; s0 < cT; s0 += 64) {
        __syncthreads();   // prior tile's PV done reading LDS
        *(bf16x8*)&ksh[sr * 72 + sc] = k0; *(bf16x8*)&ksh[sr * 72 + sc + 8] = k1;
        *(bf16x8*)&ksl[sr * 72 + sc] = k2; *(bf16x8*)&ksl[sr * 72 + sc + 8] = k3;
        *(bf16x8*)&vs[sr * 72 + sc] = v0;  *(bf16x8*)&vs[sr * 72 + sc + 8] = v1;
        __syncthreads();
        if (s0 + 64 < cT) {   // issue next tile loads; covered by QK+softmax+PV below
            size_t koff = ((size_t)bh * cT + s0 + 64 + sr) * cD + sc;
            k0 = *(const bf16x8*)(khh + koff); k1 = *(const bf16x8*)(khh + koff + 8);
            k2 = *(const bf16x8*)(khl + koff); k3 = *(const bf16x8*)(khl + koff + 8);
            size_t voff = ((size_t)bh * cD + sr) * cT + s0 + 64 + sc;
            v0 = *(const bf16x8*)(vt + voff);  v1 = *(const bf16x8*)(vt + voff + 8);
        }
        for (int j = 0; j < 4; j++) {
            bf16x8 bh0 = *(const bf16x8*)&ksh[(j * 16 + fr) * 72 + kq];
            bf16x8 bh1 = *(const bf16x8*)&ksh[(j * 16 + fr) * 72 + 32 + kq];
            bf16x8 bl0 = *(const bf16x8*)&ksl[(j * 16 + fr) * 72 + kq];
            bf16x8 bl1 = *(const bf16x8*)&ksl[(j * 16 + fr) * 72 + 32 + kq];
            f32x4 acc = qk6(ah0, ah1, al0, al1, bh0, bh1, bl0, bl1);
            int scol = s0 + j * 16 + fr;
            for (int r4 = 0; r4 < 4; r4++) {
                float p = expf(acc[r4] - mloc[r4]) * linv[r4];
                _Float16 p16 = (_Float16)p;           // reference casts w to f16
                float pf = (float)p16;                // exact
                int qrl = wid * 16 + g * 4 + r4;
                psh[qrl * 72 + j * 16 + fr] = f16_bits(p16);   // f16 MFMA operand
                size_t oidx = ((size_t)((h * cB + b) * cT + q0 + qrl)) * cT + scol;
                __builtin_nontemporal_store(pf, &out1[oidx]);  // write-once stream
            }
        }
        __syncthreads();
        __builtin_amdgcn_s_setprio(1);
        for (int kc = 0; kc < 2; kc++) {
            f16x8 pa = *(const f16x8*)&psh[(wid * 16 + fr) * 72 + kc * 32 + kq];
            for (int nf = 0; nf < 4; nf++) {
                f16x8 vb = *(const f16x8*)&vs[(nf * 16 + fr) * 72 + kc * 32 + kq];
                od[nf] = __builtin_amdgcn_mfma_f32_16x16x32_f16(pa, vb, od[nf], 0, 0, 0);
            }
        }
        __builtin_amdgcn_s_setprio(0);
    }
    for (int nf = 0; nf < 4; nf++) {
        for (int r4 = 0; r4 < 4; r4++) {
            int qr = q0 + wid * 16 + g * 4 + r4;
            int col = h * cD + nf * 16 + fr;
            attnb[(size_t)(b * cT + qr) * cE + col] = bf16_rne(od[nf][r4]);
        }
    }
}

// ---------------------------------------------------------------------------
// Launch — workspace footprint 56 MB. Phase-local reuse:
//   q phase: A-split(query) at 0-16 MB (later qhh/qhl), Wq h/l at 48-52 MB
//   k phase: A-split(key) at 16-32 MB (later khh/khl), Wk h/l at 48-52,
//            Wv h at 52-54 (survives into v phase)
//   o phase: Wo h at 52-54 (after transpose; mrow/lrow end at 48.5 MB)
// ---------------------------------------------------------------------------
extern "C" void kernel_launch(void* const* d_in, const int* in_sizes, int n_in,
                              void* d_out, int out_size, void* d_ws, size_t ws_size,
                              hipStream_t stream) {
    (void)in_sizes; (void)n_in; (void)out_size; (void)ws_size;
    const float* query = (const float*)d_in[0];
    const float* key   = (const float*)d_in[1];
    const float* value = (const float*)d_in[2];
    const float* Wq = (const float*)d_in[3];
    const float* bq = (const float*)d_in[4];
    const float* Wk = (const float*)d_in[5];
    const float* bk = (const float*)d_in[6];
    const float* Wv = (const float*)d_in[7];
    const float* bv = (const float*)d_in[8];
    const float* Wo = (const float*)d_in[9];
    const float* bo = (const float*)d_in[10];

    char* w = (char*)d_ws;
    unsigned short* qhh = (unsigned short*)(w + 0);
    unsigned short* qhl = (unsigned short*)(w + 8388608);
    unsigned short* khh = (unsigned short*)(w + 16777216);
    unsigned short* khl = (unsigned short*)(w + 25165824);
    float*          proj = (float*)(w + 33554432);          // 16 MB, per-phase
    unsigned short* vt   = (unsigned short*)(w + 33554432); // overlays proj (dead)
    unsigned short* attnb = (unsigned short*)(w + 41943040);// overlays proj high half
    unsigned short* vh  = (unsigned short*)(w + 50331648);  // 8 MB
    float* mrow = (float*)(w + 50331648);                   // overlays vh (dead after transpose)
    float* lrow = (float*)(w + 50593792);
    // phase-local scratch
    unsigned short* wsh = (unsigned short*)(w + 50331648);  // W split h (2 MB @ 48 M)
    unsigned short* wsl = (unsigned short*)(w + 52428800);  // W split l (2 MB @ 50 M)
    unsigned short* wvh = (unsigned short*)(w + 54525952);  // Wv/Wo split h (2 MB @ 52 M)

    float* out0 = (float*)d_out;
    float* out1 = out0 + (size_t)cN * cE;

    dim3 blk(256);
    dim3 gg(8, 32);

    // ---- q phase: split query (hi/lo) + Wq (hi/lo); pure-bf16 3-pass GEMM ----
    split_hl3<<<dim3(2560), blk, 0, stream>>>(query, qhh, qhl, 2048,
                                              Wq, wsh, wsl, 512, nullptr, nullptr);
    gemm_x<3, 2><<<gg, blk, 0, stream>>>(qhh, qhl, nullptr, wsh, wsl, bq, 0.125f, proj);
    prune_xpos<<<dim3(cN), blk, 0, stream>>>(proj, 0, qhh, qhl);
    // ---- k phase: split key + Wk (hi/lo) + Wv (hi only, used in v phase) ----
    split_hl3<<<dim3(3072), blk, 0, stream>>>(key, khh, khl, 2048,
                                              Wk, wsh, wsl, 512, Wv, wvh);
    gemm_x<3, 2><<<gg, blk, 0, stream>>>(khh, khl, nullptr, wsh, wsl, bk, 1.0f, proj);
    prune_xpos<<<dim3(cN), blk, 0, stream>>>(proj, 1, khh, khl);
    // ---- v phase: A fp32 in-kernel h-convert; B = pre-split WvH ----
    gemm_x<1, 1><<<gg, blk, 0, stream>>>(nullptr, nullptr, value, wvh, nullptr, bv, 1.0f, proj);
    prune_xpos<<<dim3(cN), blk, 0, stream>>>(proj, 2, vh, nullptr);

    transpose_v<<<dim3(cT / 64, cBH), blk, 0, stream>>>(vh, vt);
    // Wo split (h only) — after transpose, 52-54 MB is free (mrow/lrow end at 48.5 MB)
    split_hl3<<<dim3(512), blk, 0, stream>>>(Wo, wvh, nullptr, 512,
                                             nullptr, nullptr, nullptr, 0, nullptr, nullptr);
    attn_ml<<<dim3(cT / 64, cBH), blk, 0, stream>>>(qhh, qhl, khh, khl, mrow, lrow);
    attn_wv<<<dim3(cT / 64, cBH), blk, 0, stream>>>(qhh, qhl, khh, khl, vt, mrow, lrow, out1, attnb);

    // out0 = attnb @ Wo^T + bo  (A bf16, B = pre-split WoH), fp32 out
    gemm_x<1, 0><<<gg, blk, 0, stream>>>(attnb, nullptr, nullptr, wvh, nullptr, bo, 1.0f, out0);
}